// Round 14
// baseline (470.919 us; speedup 1.0000x reference)
//
#include <hip/hip_runtime.h>
#include <hip/hip_bf16.h>
#include <math.h>

#define N_NODES 50000
#define N_EDGES 800000
#define HEADS 4
#define NEG 0.2f

#define SCAN_TILE 1024
#define SCAN_NB ((N_NODES + SCAN_TILE - 1) / SCAN_TILE)   // 49

// ---------- GEMM (FOUT=128): out[N,128] = h[N,FIN] @ W[FIN,128] ----------
template<int FIN>
__global__ __launch_bounds__(256) void gemm128_kernel(const float* __restrict__ h,
                                                      const float* __restrict__ W,
                                                      float* __restrict__ out) {
    constexpr int ROWS = 32;
    __shared__ float hs[ROWS][FIN];
    const int tid = threadIdx.x;
    const int rbase = blockIdx.x * ROWS;
    constexpr int VECS = ROWS * FIN / 4;
    for (int i = tid; i < VECS; i += 256) {
        int r = (i * 4) / FIN, c = (i * 4) % FIN;
        int gr = rbase + r;
        float4 v = {0.f, 0.f, 0.f, 0.f};
        if (gr < N_NODES) v = *(const float4*)(h + (size_t)gr * FIN + c);
        *(float4*)(&hs[r][c]) = v;
    }
    __syncthreads();
    const int c4 = (tid & 31) * 4;
    const int r0 = (tid >> 5) * 4;
    float a0[4] = {}, a1[4] = {}, a2[4] = {}, a3[4] = {};
    for (int k = 0; k < FIN; ++k) {
        const float4 w = *(const float4*)(W + k * 128 + c4);
        const float h0 = hs[r0 + 0][k], h1 = hs[r0 + 1][k];
        const float h2 = hs[r0 + 2][k], h3 = hs[r0 + 3][k];
        a0[0] += h0 * w.x; a0[1] += h0 * w.y; a0[2] += h0 * w.z; a0[3] += h0 * w.w;
        a1[0] += h1 * w.x; a1[1] += h1 * w.y; a1[2] += h1 * w.z; a1[3] += h1 * w.w;
        a2[0] += h2 * w.x; a2[1] += h2 * w.y; a2[2] += h2 * w.z; a2[3] += h2 * w.w;
        a3[0] += h3 * w.x; a3[1] += h3 * w.y; a3[2] += h3 * w.z; a3[3] += h3 * w.w;
    }
    float* rows[4] = {a0, a1, a2, a3};
#pragma unroll
    for (int i = 0; i < 4; ++i) {
        int gr = rbase + r0 + i;
        if (gr < N_NODES) {
            float4 v = {rows[i][0], rows[i][1], rows[i][2], rows[i][3]};
            *(float4*)(out + (size_t)gr * 128 + c4) = v;
        }
    }
}

// ---------- GEMM generic (FOUT=32 final layer) ----------
template<int FIN, int FOUT>
__global__ __launch_bounds__(128) void gemm_kernel(const float* __restrict__ h,
                                                   const float* __restrict__ W,
                                                   float* __restrict__ out) {
    constexpr int ROWS = 16;
    constexpr int SUBS = 128 / FOUT;
    constexpr int RPT  = ROWS / SUBS;
    __shared__ float hs[ROWS][FIN];
    const int tid = threadIdx.x;
    const int rbase = blockIdx.x * ROWS;
    for (int i = tid; i < ROWS * FIN; i += 128) {
        int r = i / FIN, c = i % FIN;
        int gr = rbase + r;
        hs[r][c] = (gr < N_NODES) ? h[(size_t)gr * FIN + c] : 0.f;
    }
    __syncthreads();
    const int col = tid % FOUT;
    const int sub = tid / FOUT;
    float acc[RPT];
#pragma unroll
    for (int i = 0; i < RPT; ++i) acc[i] = 0.f;
    for (int k = 0; k < FIN; ++k) {
        float w = W[k * FOUT + col];
#pragma unroll
        for (int i = 0; i < RPT; ++i) acc[i] += hs[sub * RPT + i][k] * w;
    }
#pragma unroll
    for (int i = 0; i < RPT; ++i) {
        int gr = rbase + sub * RPT + i;
        if (gr < N_NODES) out[(size_t)gr * FOUT + col] = acc[i];
    }
}

// ---------- CSR build ----------
__global__ __launch_bounds__(256) void deg_count(const int* __restrict__ dst,
                                                 int* __restrict__ deg) {
    int e = blockIdx.x * blockDim.x + threadIdx.x;
    if (e < N_EDGES) atomicAdd(&deg[dst[e]], 1);
}

// k1: per-tile reduce -> bsum[b]
__global__ __launch_bounds__(256) void scan_reduce(const int* __restrict__ deg,
                                                   int* __restrict__ bsum) {
    __shared__ int wtot[4];
    const int tid = threadIdx.x;
    const int base = blockIdx.x * SCAN_TILE + tid * 4;
    int s = 0;
    if (base < N_NODES) {
        int4 v = *(const int4*)(deg + base);
        s = v.x + v.y + v.z + v.w;
    }
#pragma unroll
    for (int off = 1; off < 64; off <<= 1) s += __shfl_xor(s, off, 64);
    if ((tid & 63) == 0) wtot[tid >> 6] = s;
    __syncthreads();
    if (tid == 0) bsum[blockIdx.x] = wtot[0] + wtot[1] + wtot[2] + wtot[3];
}

// k2: tile scan + global offset -> row_ptr[0..N], woff[0..N)
__global__ __launch_bounds__(256) void scan_write(const int* __restrict__ deg,
                                                  const int* __restrict__ bsum,
                                                  int* __restrict__ row_ptr,
                                                  int* __restrict__ woff) {
    __shared__ int s_boff;
    __shared__ int wtot[4];
    const int tid  = threadIdx.x;
    const int lane = tid & 63;
    const int wid  = tid >> 6;
    const int b    = blockIdx.x;
    if (wid == 0) {
        int v = (lane < b) ? bsum[lane] : 0;
#pragma unroll
        for (int off = 1; off < 64; off <<= 1) v += __shfl_xor(v, off, 64);
        if (lane == 0) s_boff = v;
    }
    const int base = b * SCAN_TILE + tid * 4;
    int4 v = {0, 0, 0, 0};
    if (base < N_NODES) v = *(const int4*)(deg + base);
    const int t0 = v.x, t1 = t0 + v.y, t2 = t1 + v.z, t3 = t2 + v.w;
    int x = t3;
#pragma unroll
    for (int off = 1; off < 64; off <<= 1) {
        int t = __shfl_up(x, off, 64);
        if (lane >= off) x += t;
    }
    if (lane == 63) wtot[wid] = x;
    __syncthreads();
    int woffs = 0;
    for (int w = 0; w < wid; ++w) woffs += wtot[w];
    const int off0 = s_boff + woffs + (x - t3);
    if (base < N_NODES) {
        row_ptr[base + 1] = off0 + t0;  woff[base + 0] = off0 + t0 - v.x;
        row_ptr[base + 2] = off0 + t1;  woff[base + 1] = off0 + t1 - v.y;
        row_ptr[base + 3] = off0 + t2;  woff[base + 2] = off0 + t2 - v.z;
        row_ptr[base + 4] = off0 + t3;  woff[base + 3] = off0 + t3 - v.w;
    }
    if (b == 0 && tid == 0) row_ptr[0] = 0;
}

__global__ __launch_bounds__(256) void scatter_kernel(const int* __restrict__ src,
                                                      const int* __restrict__ dst,
                                                      int* __restrict__ woff,
                                                      int* __restrict__ csr_src) {
    int e = blockIdx.x * blockDim.x + threadIdx.x;
    if (e < N_EDGES) {
        int pos = atomicAdd(&woff[dst[e]], 1);
        csr_src[pos] = src[e];
    }
}

// ---------- fused dst-centric GATv2 layer, EDGE-PARALLEL ----------
// One node per wave. EPAR = 64/LPN edge slots run concurrently; UNR-deep
// unroll -> EPAR*UNR gathers in flight. Per-slot online-softmax state
// (m,s,acc) merged at the end via shfl_xor softmax-merge.
// NaN guard: p must be forced to 0 for inactive slots (exp(-inf - -inf) = NaN).
template<int D, int MODE>
__global__ __launch_bounds__(256) void fused_gat(const float* __restrict__ feat,
                                                 const int* __restrict__ row_ptr,
                                                 const int* __restrict__ csr_src,
                                                 const float* __restrict__ attn,
                                                 float* __restrict__ out) {
    constexpr int F    = HEADS * D;     // floats per row (128 or 32)
    constexpr int LPN  = F / 4;         // lanes per row copy (32 or 8)
    constexpr int EPAR = 64 / LPN;      // concurrent edge slots (2 or 8)
    constexpr int UNR  = (D == 32) ? 4 : 2;
    constexpr int CHUNK = EPAR * UNR;   // edges per iteration (8 or 16)
    const int lane = threadIdx.x & 63;
    const int v    = (blockIdx.x * blockDim.x + threadIdx.x) >> 6;  // node = wave
    if (v >= N_NODES) return;
    const int slot = lane / LPN;
    const int l    = lane % LPN;

    const float4 a4 = *(const float4*)(attn + l * 4);
    const float4 fv = *(const float4*)(feat + (size_t)v * F + l * 4);

    float m = -INFINITY, s = 0.f;
    float4 acc = {0.f, 0.f, 0.f, 0.f};

    const int beg = row_ptr[v], end = row_ptr[v + 1];
    for (int jc = beg; jc < end; jc += CHUNK) {
        int    idx[UNR];
        bool   act[UNR];
        float4 fr[UNR];
        float  sc[UNR];
#pragma unroll
        for (int u = 0; u < UNR; ++u) {
            const int j = jc + u * EPAR + slot;
            act[u] = (j < end);
            idx[u] = act[u] ? csr_src[j] : v;   // safe in-range row for inactive
        }
#pragma unroll
        for (int u = 0; u < UNR; ++u)
            fr[u] = *(const float4*)(feat + (size_t)idx[u] * F + l * 4);
#pragma unroll
        for (int u = 0; u < UNR; ++u) {
            float t, x;
            t = fr[u].x + fv.x; t = t > 0.f ? t : t * NEG; x  = t * a4.x;
            t = fr[u].y + fv.y; t = t > 0.f ? t : t * NEG; x += t * a4.y;
            t = fr[u].z + fv.z; t = t > 0.f ? t : t * NEG; x += t * a4.z;
            t = fr[u].w + fv.w; t = t > 0.f ? t : t * NEG; x += t * a4.w;
            sc[u] = x;
        }
#pragma unroll
        for (int off = 1; off < D / 4; off <<= 1) {
#pragma unroll
            for (int u = 0; u < UNR; ++u)
                sc[u] += __shfl_xor(sc[u], off, 64);
        }
#pragma unroll
        for (int u = 0; u < UNR; ++u)
            if (!act[u]) sc[u] = -INFINITY;
        float scmax = sc[0];
#pragma unroll
        for (int u = 1; u < UNR; ++u) scmax = fmaxf(scmax, sc[u]);
        if (scmax > m) {                    // uniform within each slot group
            const float scale = __expf(m - scmax);   // m=-inf -> 0
            s *= scale;
            acc.x *= scale; acc.y *= scale; acc.z *= scale; acc.w *= scale;
            m = scmax;
        }
#pragma unroll
        for (int u = 0; u < UNR; ++u) {
            // NaN guard: inactive slot with m==-inf would give exp(-inf+inf)=NaN
            const float p = act[u] ? __expf(sc[u] - m) : 0.f;
            s += p;
            acc.x += fr[u].x * p;
            acc.y += fr[u].y * p;
            acc.z += fr[u].z * p;
            acc.w += fr[u].w * p;
        }
    }

    // merge the EPAR per-slot states (softmax-merge), levels LPN..32
#pragma unroll
    for (int off = LPN; off < 64; off <<= 1) {
        const float mo = __shfl_xor(m, off, 64);
        const float so = __shfl_xor(s, off, 64);
        float4 ao;
        ao.x = __shfl_xor(acc.x, off, 64);
        ao.y = __shfl_xor(acc.y, off, 64);
        ao.z = __shfl_xor(acc.z, off, 64);
        ao.w = __shfl_xor(acc.w, off, 64);
        const float mM = fmaxf(m, mo);
        const float f  = (m  < mM) ? __expf(m  - mM) : 1.f;   // -inf-safe
        const float fo = (mo < mM) ? __expf(mo - mM) : 1.f;
        s = s * f + so * fo;
        acc.x = acc.x * f + ao.x * fo;
        acc.y = acc.y * f + ao.y * fo;
        acc.z = acc.z * f + ao.z * fo;
        acc.w = acc.w * f + ao.w * fo;
        m = mM;
    }

    const float inv = (s > 0.f) ? 1.f / s : 0.f;
    float4 r;
    r.x = acc.x * inv; r.y = acc.y * inv; r.z = acc.z * inv; r.w = acc.w * inv;
    if (MODE == 0) {
        if (slot == 0) {
            r.x = r.x > 0.f ? r.x : expm1f(r.x);
            r.y = r.y > 0.f ? r.y : expm1f(r.y);
            r.z = r.z > 0.f ? r.z : expm1f(r.z);
            r.w = r.w > 0.f ? r.w : expm1f(r.w);
            *(float4*)(out + (size_t)v * F + l * 4) = r;
        }
    } else {
        // mean over heads: head bits are l's bits 1..2 (D=8: l = head*2 + dpos/4)
        r.x += __shfl_xor(r.x, 2, 64); r.y += __shfl_xor(r.y, 2, 64);
        r.z += __shfl_xor(r.z, 2, 64); r.w += __shfl_xor(r.w, 2, 64);
        r.x += __shfl_xor(r.x, 4, 64); r.y += __shfl_xor(r.y, 4, 64);
        r.z += __shfl_xor(r.z, 4, 64); r.w += __shfl_xor(r.w, 4, 64);
        if (slot == 0 && l < 2) {
            r.x *= 0.25f; r.y *= 0.25f; r.z *= 0.25f; r.w *= 0.25f;
            *(float4*)(out + (size_t)v * 8 + l * 4) = r;
        }
    }
}

extern "C" void kernel_launch(void* const* d_in, const int* in_sizes, int n_in,
                              void* d_out, int out_size, void* d_ws, size_t ws_size,
                              hipStream_t stream) {
    const float* features = (const float*)d_in[0];
    const float* W0 = (const float*)d_in[1];  const float* attn0 = (const float*)d_in[2];
    const float* W1 = (const float*)d_in[3];  const float* attn1 = (const float*)d_in[4];
    const float* W2 = (const float*)d_in[5];  const float* attn2 = (const float*)d_in[6];
    const float* W3 = (const float*)d_in[7];  const float* attn3 = (const float*)d_in[8];
    const int* src = (const int*)d_in[9];
    const int* dst = (const int*)d_in[10];
    float* out = (float*)d_out;

    // workspace layout
    float* bufA   = (float*)d_ws;                         // N*128 f
    float* feat   = bufA + (size_t)N_NODES * 128;         // N*128 f
    int* row_ptr  = (int*)(feat + (size_t)N_NODES * 128); // N+1
    int* woff     = row_ptr + (N_NODES + 1);              // N
    int* deg      = woff + N_NODES;                       // N
    int* csr_src  = deg + N_NODES;                        // E
    int* bsum     = csr_src + N_EDGES;                    // SCAN_NB

    const int EBLK = (N_EDGES + 255) / 256;
    const int GB32 = (N_NODES + 31) / 32;
    const int GB16 = (N_NODES + 15) / 16;

    // ---- CSR build (graph static across layers) ----
    hipMemsetAsync(deg, 0, (size_t)N_NODES * 4, stream);
    deg_count<<<EBLK, 256, 0, stream>>>(dst, deg);
    scan_reduce<<<SCAN_NB, 256, 0, stream>>>(deg, bsum);
    scan_write<<<SCAN_NB, 256, 0, stream>>>(deg, bsum, row_ptr, woff);
    scatter_kernel<<<EBLK, 256, 0, stream>>>(src, dst, woff, csr_src);

    // one node per wave -> N waves -> N*64 threads
    const int FB = ((size_t)N_NODES * 64 + 255) / 256;   // 12500 blocks

    // ---- layer 0 ----
    gemm128_kernel<16><<<GB32, 256, 0, stream>>>(features, W0, feat);
    fused_gat<32, 0><<<FB, 256, 0, stream>>>(feat, row_ptr, csr_src, attn0, bufA);
    // ---- layer 1 ----
    gemm128_kernel<128><<<GB32, 256, 0, stream>>>(bufA, W1, feat);
    fused_gat<32, 0><<<FB, 256, 0, stream>>>(feat, row_ptr, csr_src, attn1, bufA);
    // ---- layer 2 ----
    gemm128_kernel<128><<<GB32, 256, 0, stream>>>(bufA, W2, feat);
    fused_gat<32, 0><<<FB, 256, 0, stream>>>(feat, row_ptr, csr_src, attn2, bufA);
    // ---- layer 3 (head-mean) ----
    gemm_kernel<128, 32><<<GB16, 128, 0, stream>>>(bufA, W3, feat);
    fused_gat<8, 1><<<FB, 256, 0, stream>>>(feat, row_ptr, csr_src, attn3, out);
}

// Round 15
// 467.861 us; speedup vs baseline: 1.0065x; 1.0065x over previous
//
#include <hip/hip_runtime.h>
#include <hip/hip_bf16.h>
#include <math.h>

#define N_NODES 50000
#define N_EDGES 800000
#define HEADS 4
#define NEG 0.2f

#define SCAN_TILE 1024
#define SCAN_NB ((N_NODES + SCAN_TILE - 1) / SCAN_TILE)   // 49

// ---------- GEMM (FOUT=128): out[N,128] = h[N,FIN] @ W[FIN,128] ----------
// 64 rows x 128 cols per block, 256 threads; thread = 8 rows x 4 cols.
// Per k: 8 LDS broadcast reads + 1 W float4 (L1) + 32 FMAs.
template<int FIN>
__global__ __launch_bounds__(256) void gemm128_kernel(const float* __restrict__ h,
                                                      const float* __restrict__ W,
                                                      float* __restrict__ out) {
    constexpr int ROWS = 64;
    __shared__ float hs[ROWS][FIN];
    const int tid = threadIdx.x;
    const int rbase = blockIdx.x * ROWS;
    constexpr int VECS = ROWS * FIN / 4;
    for (int i = tid; i < VECS; i += 256) {
        int r = (i * 4) / FIN, c = (i * 4) % FIN;
        int gr = rbase + r;
        float4 v = {0.f, 0.f, 0.f, 0.f};
        if (gr < N_NODES) v = *(const float4*)(h + (size_t)gr * FIN + c);
        *(float4*)(&hs[r][c]) = v;
    }
    __syncthreads();
    const int c4 = (tid & 31) * 4;       // 32 col-groups of 4
    const int r0 = (tid >> 5) * 8;       // 8 row-groups of 8
    float acc[8][4] = {};
    for (int k = 0; k < FIN; ++k) {
        const float4 w = *(const float4*)(W + k * 128 + c4);
#pragma unroll
        for (int i = 0; i < 8; ++i) {
            const float hv = hs[r0 + i][k];
            acc[i][0] += hv * w.x;
            acc[i][1] += hv * w.y;
            acc[i][2] += hv * w.z;
            acc[i][3] += hv * w.w;
        }
    }
#pragma unroll
    for (int i = 0; i < 8; ++i) {
        int gr = rbase + r0 + i;
        if (gr < N_NODES) {
            float4 v = {acc[i][0], acc[i][1], acc[i][2], acc[i][3]};
            *(float4*)(out + (size_t)gr * 128 + c4) = v;
        }
    }
}

// ---------- GEMM (FOUT=32): out[N,32] = h[N,128] @ W[128,32] ----------
// 64 rows/block, 256 threads = 8 col-groups x 32 row-groups; thread = 2 rows x 4 cols.
__global__ __launch_bounds__(256) void gemm32_kernel(const float* __restrict__ h,
                                                     const float* __restrict__ W,
                                                     float* __restrict__ out) {
    constexpr int FIN = 128, ROWS = 64;
    __shared__ float hs[ROWS][FIN];
    const int tid = threadIdx.x;
    const int rbase = blockIdx.x * ROWS;
    constexpr int VECS = ROWS * FIN / 4;
    for (int i = tid; i < VECS; i += 256) {
        int r = (i * 4) / FIN, c = (i * 4) % FIN;
        int gr = rbase + r;
        float4 v = {0.f, 0.f, 0.f, 0.f};
        if (gr < N_NODES) v = *(const float4*)(h + (size_t)gr * FIN + c);
        *(float4*)(&hs[r][c]) = v;
    }
    __syncthreads();
    const int c4 = (tid & 7) * 4;        // 8 col-groups of 4
    const int r0 = (tid >> 3) * 2;       // 32 row-groups of 2
    float acc[2][4] = {};
    for (int k = 0; k < FIN; ++k) {
        const float4 w = *(const float4*)(W + k * 32 + c4);   // 128 B row, L1-hit
        const float h0 = hs[r0 + 0][k], h1 = hs[r0 + 1][k];
        acc[0][0] += h0 * w.x; acc[0][1] += h0 * w.y;
        acc[0][2] += h0 * w.z; acc[0][3] += h0 * w.w;
        acc[1][0] += h1 * w.x; acc[1][1] += h1 * w.y;
        acc[1][2] += h1 * w.z; acc[1][3] += h1 * w.w;
    }
#pragma unroll
    for (int i = 0; i < 2; ++i) {
        int gr = rbase + r0 + i;
        if (gr < N_NODES) {
            float4 v = {acc[i][0], acc[i][1], acc[i][2], acc[i][3]};
            *(float4*)(out + (size_t)gr * 32 + c4) = v;
        }
    }
}

// ---------- CSR build ----------
__global__ __launch_bounds__(256) void deg_count(const int* __restrict__ dst,
                                                 int* __restrict__ deg) {
    int e = blockIdx.x * blockDim.x + threadIdx.x;
    if (e < N_EDGES) atomicAdd(&deg[dst[e]], 1);
}

// k1: per-tile reduce -> bsum[b]
__global__ __launch_bounds__(256) void scan_reduce(const int* __restrict__ deg,
                                                   int* __restrict__ bsum) {
    __shared__ int wtot[4];
    const int tid = threadIdx.x;
    const int base = blockIdx.x * SCAN_TILE + tid * 4;
    int s = 0;
    if (base < N_NODES) {
        int4 v = *(const int4*)(deg + base);
        s = v.x + v.y + v.z + v.w;
    }
#pragma unroll
    for (int off = 1; off < 64; off <<= 1) s += __shfl_xor(s, off, 64);
    if ((tid & 63) == 0) wtot[tid >> 6] = s;
    __syncthreads();
    if (tid == 0) bsum[blockIdx.x] = wtot[0] + wtot[1] + wtot[2] + wtot[3];
}

// k2: tile scan + global offset -> row_ptr[0..N], woff[0..N)
__global__ __launch_bounds__(256) void scan_write(const int* __restrict__ deg,
                                                  const int* __restrict__ bsum,
                                                  int* __restrict__ row_ptr,
                                                  int* __restrict__ woff) {
    __shared__ int s_boff;
    __shared__ int wtot[4];
    const int tid  = threadIdx.x;
    const int lane = tid & 63;
    const int wid  = tid >> 6;
    const int b    = blockIdx.x;
    if (wid == 0) {
        int v = (lane < b) ? bsum[lane] : 0;
#pragma unroll
        for (int off = 1; off < 64; off <<= 1) v += __shfl_xor(v, off, 64);
        if (lane == 0) s_boff = v;
    }
    const int base = b * SCAN_TILE + tid * 4;
    int4 v = {0, 0, 0, 0};
    if (base < N_NODES) v = *(const int4*)(deg + base);
    const int t0 = v.x, t1 = t0 + v.y, t2 = t1 + v.z, t3 = t2 + v.w;
    int x = t3;
#pragma unroll
    for (int off = 1; off < 64; off <<= 1) {
        int t = __shfl_up(x, off, 64);
        if (lane >= off) x += t;
    }
    if (lane == 63) wtot[wid] = x;
    __syncthreads();
    int woffs = 0;
    for (int w = 0; w < wid; ++w) woffs += wtot[w];
    const int off0 = s_boff + woffs + (x - t3);
    if (base < N_NODES) {
        row_ptr[base + 1] = off0 + t0;  woff[base + 0] = off0 + t0 - v.x;
        row_ptr[base + 2] = off0 + t1;  woff[base + 1] = off0 + t1 - v.y;
        row_ptr[base + 3] = off0 + t2;  woff[base + 2] = off0 + t2 - v.z;
        row_ptr[base + 4] = off0 + t3;  woff[base + 3] = off0 + t3 - v.w;
    }
    if (b == 0 && tid == 0) row_ptr[0] = 0;
}

__global__ __launch_bounds__(256) void scatter_kernel(const int* __restrict__ src,
                                                      const int* __restrict__ dst,
                                                      int* __restrict__ woff,
                                                      int* __restrict__ csr_src) {
    int e = blockIdx.x * blockDim.x + threadIdx.x;
    if (e < N_EDGES) {
        int pos = atomicAdd(&woff[dst[e]], 1);
        csr_src[pos] = src[e];
    }
}

// ---------- fused dst-centric GATv2 layer, EDGE-PARALLEL (unchanged, at floor) ----------
template<int D, int MODE>
__global__ __launch_bounds__(256) void fused_gat(const float* __restrict__ feat,
                                                 const int* __restrict__ row_ptr,
                                                 const int* __restrict__ csr_src,
                                                 const float* __restrict__ attn,
                                                 float* __restrict__ out) {
    constexpr int F    = HEADS * D;     // floats per row (128 or 32)
    constexpr int LPN  = F / 4;         // lanes per row copy (32 or 8)
    constexpr int EPAR = 64 / LPN;      // concurrent edge slots (2 or 8)
    constexpr int UNR  = (D == 32) ? 4 : 2;
    constexpr int CHUNK = EPAR * UNR;   // edges per iteration (8 or 16)
    const int lane = threadIdx.x & 63;
    const int v    = (blockIdx.x * blockDim.x + threadIdx.x) >> 6;  // node = wave
    if (v >= N_NODES) return;
    const int slot = lane / LPN;
    const int l    = lane % LPN;

    const float4 a4 = *(const float4*)(attn + l * 4);
    const float4 fv = *(const float4*)(feat + (size_t)v * F + l * 4);

    float m = -INFINITY, s = 0.f;
    float4 acc = {0.f, 0.f, 0.f, 0.f};

    const int beg = row_ptr[v], end = row_ptr[v + 1];
    for (int jc = beg; jc < end; jc += CHUNK) {
        int    idx[UNR];
        bool   act[UNR];
        float4 fr[UNR];
        float  sc[UNR];
#pragma unroll
        for (int u = 0; u < UNR; ++u) {
            const int j = jc + u * EPAR + slot;
            act[u] = (j < end);
            idx[u] = act[u] ? csr_src[j] : v;   // safe in-range row for inactive
        }
#pragma unroll
        for (int u = 0; u < UNR; ++u)
            fr[u] = *(const float4*)(feat + (size_t)idx[u] * F + l * 4);
#pragma unroll
        for (int u = 0; u < UNR; ++u) {
            float t, x;
            t = fr[u].x + fv.x; t = t > 0.f ? t : t * NEG; x  = t * a4.x;
            t = fr[u].y + fv.y; t = t > 0.f ? t : t * NEG; x += t * a4.y;
            t = fr[u].z + fv.z; t = t > 0.f ? t : t * NEG; x += t * a4.z;
            t = fr[u].w + fv.w; t = t > 0.f ? t : t * NEG; x += t * a4.w;
            sc[u] = x;
        }
#pragma unroll
        for (int off = 1; off < D / 4; off <<= 1) {
#pragma unroll
            for (int u = 0; u < UNR; ++u)
                sc[u] += __shfl_xor(sc[u], off, 64);
        }
#pragma unroll
        for (int u = 0; u < UNR; ++u)
            if (!act[u]) sc[u] = -INFINITY;
        float scmax = sc[0];
#pragma unroll
        for (int u = 1; u < UNR; ++u) scmax = fmaxf(scmax, sc[u]);
        if (scmax > m) {                    // uniform within each slot group
            const float scale = __expf(m - scmax);   // m=-inf -> 0
            s *= scale;
            acc.x *= scale; acc.y *= scale; acc.z *= scale; acc.w *= scale;
            m = scmax;
        }
#pragma unroll
        for (int u = 0; u < UNR; ++u) {
            // NaN guard: inactive slot with m==-inf would give exp(-inf+inf)=NaN
            const float p = act[u] ? __expf(sc[u] - m) : 0.f;
            s += p;
            acc.x += fr[u].x * p;
            acc.y += fr[u].y * p;
            acc.z += fr[u].z * p;
            acc.w += fr[u].w * p;
        }
    }

    // merge the EPAR per-slot states (softmax-merge), levels LPN..32
#pragma unroll
    for (int off = LPN; off < 64; off <<= 1) {
        const float mo = __shfl_xor(m, off, 64);
        const float so = __shfl_xor(s, off, 64);
        float4 ao;
        ao.x = __shfl_xor(acc.x, off, 64);
        ao.y = __shfl_xor(acc.y, off, 64);
        ao.z = __shfl_xor(acc.z, off, 64);
        ao.w = __shfl_xor(acc.w, off, 64);
        const float mM = fmaxf(m, mo);
        const float f  = (m  < mM) ? __expf(m  - mM) : 1.f;   // -inf-safe
        const float fo = (mo < mM) ? __expf(mo - mM) : 1.f;
        s = s * f + so * fo;
        acc.x = acc.x * f + ao.x * fo;
        acc.y = acc.y * f + ao.y * fo;
        acc.z = acc.z * f + ao.z * fo;
        acc.w = acc.w * f + ao.w * fo;
        m = mM;
    }

    const float inv = (s > 0.f) ? 1.f / s : 0.f;
    float4 r;
    r.x = acc.x * inv; r.y = acc.y * inv; r.z = acc.z * inv; r.w = acc.w * inv;
    if (MODE == 0) {
        if (slot == 0) {
            r.x = r.x > 0.f ? r.x : expm1f(r.x);
            r.y = r.y > 0.f ? r.y : expm1f(r.y);
            r.z = r.z > 0.f ? r.z : expm1f(r.z);
            r.w = r.w > 0.f ? r.w : expm1f(r.w);
            *(float4*)(out + (size_t)v * F + l * 4) = r;
        }
    } else {
        r.x += __shfl_xor(r.x, 2, 64); r.y += __shfl_xor(r.y, 2, 64);
        r.z += __shfl_xor(r.z, 2, 64); r.w += __shfl_xor(r.w, 2, 64);
        r.x += __shfl_xor(r.x, 4, 64); r.y += __shfl_xor(r.y, 4, 64);
        r.z += __shfl_xor(r.z, 4, 64); r.w += __shfl_xor(r.w, 4, 64);
        if (slot == 0 && l < 2) {
            r.x *= 0.25f; r.y *= 0.25f; r.z *= 0.25f; r.w *= 0.25f;
            *(float4*)(out + (size_t)v * 8 + l * 4) = r;
        }
    }
}

extern "C" void kernel_launch(void* const* d_in, const int* in_sizes, int n_in,
                              void* d_out, int out_size, void* d_ws, size_t ws_size,
                              hipStream_t stream) {
    const float* features = (const float*)d_in[0];
    const float* W0 = (const float*)d_in[1];  const float* attn0 = (const float*)d_in[2];
    const float* W1 = (const float*)d_in[3];  const float* attn1 = (const float*)d_in[4];
    const float* W2 = (const float*)d_in[5];  const float* attn2 = (const float*)d_in[6];
    const float* W3 = (const float*)d_in[7];  const float* attn3 = (const float*)d_in[8];
    const int* src = (const int*)d_in[9];
    const int* dst = (const int*)d_in[10];
    float* out = (float*)d_out;

    // workspace layout
    float* bufA   = (float*)d_ws;                         // N*128 f
    float* feat   = bufA + (size_t)N_NODES * 128;         // N*128 f
    int* row_ptr  = (int*)(feat + (size_t)N_NODES * 128); // N+1
    int* woff     = row_ptr + (N_NODES + 1);              // N
    int* deg      = woff + N_NODES;                       // N
    int* csr_src  = deg + N_NODES;                        // E
    int* bsum     = csr_src + N_EDGES;                    // SCAN_NB

    const int EBLK = (N_EDGES + 255) / 256;
    const int GB64 = (N_NODES + 63) / 64;    // 64-row gemm blocks

    // ---- CSR build (graph static across layers) ----
    hipMemsetAsync(deg, 0, (size_t)N_NODES * 4, stream);
    deg_count<<<EBLK, 256, 0, stream>>>(dst, deg);
    scan_reduce<<<SCAN_NB, 256, 0, stream>>>(deg, bsum);
    scan_write<<<SCAN_NB, 256, 0, stream>>>(deg, bsum, row_ptr, woff);
    scatter_kernel<<<EBLK, 256, 0, stream>>>(src, dst, woff, csr_src);

    // one node per wave -> N waves -> N*64 threads
    const int FB = ((size_t)N_NODES * 64 + 255) / 256;   // 12500 blocks

    // ---- layer 0 ----
    gemm128_kernel<16><<<GB64, 256, 0, stream>>>(features, W0, feat);
    fused_gat<32, 0><<<FB, 256, 0, stream>>>(feat, row_ptr, csr_src, attn0, bufA);
    // ---- layer 1 ----
    gemm128_kernel<128><<<GB64, 256, 0, stream>>>(bufA, W1, feat);
    fused_gat<32, 0><<<FB, 256, 0, stream>>>(feat, row_ptr, csr_src, attn1, bufA);
    // ---- layer 2 ----
    gemm128_kernel<128><<<GB64, 256, 0, stream>>>(bufA, W2, feat);
    fused_gat<32, 0><<<FB, 256, 0, stream>>>(feat, row_ptr, csr_src, attn2, bufA);
    // ---- layer 3 (head-mean) ----
    gemm32_kernel<<<GB64, 256, 0, stream>>>(bufA, W3, feat);
    fused_gat<8, 1><<<FB, 256, 0, stream>>>(feat, row_ptr, csr_src, attn3, out);
}